// Round 1
// baseline (260.668 us; speedup 1.0000x reference)
//
#include <hip/hip_runtime.h>

// ---------------- problem constants ----------------
#define NQ        300
#define NC        80
#define NE        24000      // NQ*NC
#define CAND      1000
#define KSEL      100
#define NPAIRS    4000000
#define HB        4096       // score histogram buckets (float bits >> 18)
#define FHW       65536      // 256*256
#define NMS_THR_F 0.65f
#define MAPS_INIT 0x39E3BFFFu   // order-preserving encode of -1e4f

// order-preserving float->u32 encode (monotone: larger float => larger uint)
__device__ __forceinline__ unsigned enc_f32(float f) {
    unsigned u = __float_as_uint(f);
    return (u & 0x80000000u) ? ~u : (u | 0x80000000u);
}
__device__ __forceinline__ float dec_f32(unsigned k) {
    unsigned u = (k & 0x80000000u) ? (k ^ 0x80000000u) : ~k;
    return __uint_as_float(u);
}

// ---------------- K1: fused {maps init | select+sort} ----------------
// block 0: sigmoid scores -> top-1000 sorted candidates (single-CU path)
// blocks 1..1600: init compacted maps to encode(-1e4)  (hidden under block 0)
__global__ __launch_bounds__(1024) void k_init_select(
    const float* __restrict__ cls,        // [300,81]
    const float* __restrict__ pboxes,     // [300,4]
    float4* __restrict__ cboxes, float* __restrict__ cscore,
    int* __restrict__ cfeat, int* __restrict__ clabel,
    uint4* __restrict__ maps)
{
    __shared__ unsigned long long sbuf[4096];          // 32 KB, aliases hist
    unsigned* hist = (unsigned*)sbuf;                  // first 16 KB
    __shared__ unsigned subhist[64];
    __shared__ int sB, sT, sAbove, sCount, sN;
    int tid = threadIdx.x;

    if (blockIdx.x != 0) {                             // init blocks: 1600*1024 uint4 exact
        int i = (blockIdx.x - 1) * 1024 + tid;
        uint4 v; v.x = v.y = v.z = v.w = MAPS_INIT;
        maps[i] = v;
        return;
    }

    for (int b = tid; b < HB; b += 1024) hist[b] = 0u;
    if (tid < 64) subhist[tid] = 0u;
    __syncthreads();

    unsigned long long lk[24];
    #pragma unroll
    for (int k = 0; k < 24; k++) {
        int e = tid + (k << 10);
        if (e < NE) {
            int q = e / NC, c = e - q * NC;
            float x = cls[q * (NC + 1) + c];
            float s = 1.f / (1.f + expf(-x));          // scores in (0,1) -> bits monotone
            unsigned bits = __float_as_uint(s);
            lk[k] = ((unsigned long long)bits << 32) | (unsigned)(0xFFFFFFFFu - (unsigned)e);
            atomicAdd(&hist[bits >> 18], 1u);
        }
    }
    __syncthreads();

    if (tid == 0) {
        int acc = 0, B = 0;
        for (int b = HB - 1; b >= 0; b--) {            // top buckets ~empty; ~50 iters
            acc += (int)hist[b];
            if (acc >= CAND) { B = b; break; }
        }
        sB = B; sAbove = acc - (int)hist[B]; sCount = 0;
    }
    __syncthreads();
    unsigned B = (unsigned)sB;

    #pragma unroll
    for (int k = 0; k < 24; k++) {                     // sub-histogram of bucket B
        int e = tid + (k << 10);
        if (e < NE && (unsigned)(lk[k] >> 50) == B)
            atomicAdd(&subhist[(unsigned)(lk[k] >> 44) & 63u], 1u);
    }
    __syncthreads();
    if (tid == 0) {
        int acc2 = sAbove, T = 0;
        for (int t = 63; t >= 0; t--) {
            acc2 += (int)subhist[t];
            if (acc2 >= CAND) { T = t; break; }
        }
        sT = T; sN = acc2;                             // n in [1000, 1000+subbucket]
    }
    __syncthreads();
    unsigned T = (unsigned)sT;

    #pragma unroll
    for (int k = 0; k < 24; k++) {                     // compact qualifying keys
        int e = tid + (k << 10);
        if (e < NE) {
            unsigned long long key = lk[k];
            unsigned bkt = (unsigned)(key >> 50);
            unsigned sub = (unsigned)(key >> 44) & 63u;
            if (bkt > B || (bkt == B && sub >= T)) {
                int pos = atomicAdd(&sCount, 1);
                if (pos < 4096) sbuf[pos] = key;
            }
        }
    }
    __syncthreads();
    int n = min(sN, 4096);

    if (n <= 1024) {
        // fast path: one key per thread, descending bitonic, shfl for j<64
        unsigned long long r = (tid < n) ? sbuf[tid] : 0ULL;
        for (int k = 2; k <= 1024; k <<= 1) {
            for (int j = k >> 1; j > 0; j >>= 1) {
                unsigned long long p;
                if (j >= 64) {
                    sbuf[tid] = r; __syncthreads();
                    p = sbuf[tid ^ j]; __syncthreads();
                } else {
                    p = __shfl_xor(r, j, 64);
                }
                bool d = (tid & k) != 0, lower = (tid & j) == 0;
                r = (d != lower) ? (r > p ? r : p) : (r < p ? r : p);
            }
        }
        sbuf[tid] = r;
        __syncthreads();
    } else {
        // fallback: generic LDS bitonic over next pow2
        int nsort = 2048; while (nsort < n) nsort <<= 1;
        for (int i = n + tid; i < nsort; i += 1024) sbuf[i] = 0ULL;
        __syncthreads();
        for (int k = 2; k <= nsort; k <<= 1) {
            for (int j = k >> 1; j > 0; j >>= 1) {
                for (int i = tid; i < nsort; i += 1024) {
                    int ixj = i ^ j;
                    if (ixj > i) {
                        unsigned long long a = sbuf[i], b = sbuf[ixj];
                        bool up = ((i & k) == 0);
                        if (up ? (a < b) : (a > b)) { sbuf[i] = b; sbuf[ixj] = a; }
                    }
                }
                __syncthreads();
            }
        }
    }

    if (tid < CAND) {
        unsigned long long key = sbuf[tid];
        unsigned bits = (unsigned)(key >> 32);
        unsigned e = 0xFFFFFFFFu - (unsigned)(key & 0xFFFFFFFFu);
        int feat = (int)e / NC, lab = (int)e - feat * NC;
        cscore[tid] = __uint_as_float(bits);
        cfeat[tid]  = feat;
        clabel[tid] = lab;
        float off = 4.f * (float)lab;                  // class-aware box offset
        float4 b;
        b.x = pboxes[feat * 4 + 0] + off; b.y = pboxes[feat * 4 + 1] + off;
        b.z = pboxes[feat * 4 + 2] + off; b.w = pboxes[feat * 4 + 3] + off;
        cboxes[tid] = b;
    }
}

// ---------------- K2: fused {per-label NMS + first-100 pick} ----------------
// one block, 1024 threads = 16 waves. Wave w handles labels w, w+16, ... (5 each).
// keepflags live in LDS; pick phase runs after one barrier (no global round-trip).
__global__ __launch_bounds__(1024) void k_nms_pick(
    const float4* __restrict__ cboxes, const int* __restrict__ clabel,
    const float* __restrict__ cscore, const int* __restrict__ cfeat,
    float* __restrict__ sel_score, int* __restrict__ sel_slot,
    int* __restrict__ qry2slot,
    const unsigned* __restrict__ refined_raw, unsigned* __restrict__ mode_flag)
{
    __shared__ int list[16][256];                      // per-wave label member list
    __shared__ int keepf[CAND];
    __shared__ float ss[KSEL];
    __shared__ int   sf[KSEL];
    __shared__ int   q2s[NQ];
    __shared__ unsigned smode;
    __shared__ int sbase;

    int tid  = threadIdx.x;
    int wave = tid >> 6, lane = tid & 63;
    int* mylist = list[wave];

    for (int i = tid; i < CAND; i += 1024) keepf[i] = 0;   // labels with >256 members: tail dropped
    for (int q = tid; q < NQ; q += 1024) q2s[q] = -1;
    __syncthreads();

    for (int lab = wave; lab < NC; lab += 16) {
        int base = 0;
        for (int c = 0; c < CAND; c += 64) {           // ordered compaction of this label
            int i = c + lane;
            bool m = (i < CAND) && (clabel[i] == lab);
            unsigned long long bal = __ballot(m);
            int rank = __popcll(bal & ((1ULL << lane) - 1ULL));
            if (m && base + rank < 256) mylist[base + rank] = i;
            base += __popcll(bal);
        }
        int n = min(base, 256);

        float4 bx[4]; float area[4];
        unsigned keepm = 0;
        #pragma unroll
        for (int s = 0; s < 4; s++) {
            int j = (s << 6) + lane;
            if (j < n) {
                bx[s] = cboxes[mylist[j]];
                area[s] = (bx[s].z - bx[s].x) * (bx[s].w - bx[s].y);
                keepm |= (1u << s);
            }
        }
        #pragma unroll
        for (int slot = 0; slot < 4; slot++) {         // sequential greedy over this label
            int i0 = slot << 6;
            if (i0 >= n) break;
            int iend = min(64, n - i0);
            for (int l = 0; l < iend; l++) {
                int i = i0 + l;
                unsigned km = __shfl(keepm, l);
                bool keep_i = (km >> slot) & 1u;       // uniform
                float bix = __shfl(bx[slot].x, l), biy = __shfl(bx[slot].y, l);
                float biz = __shfl(bx[slot].z, l), biw = __shfl(bx[slot].w, l);
                float ai  = __shfl(area[slot], l);
                if (keep_i) {
                    #pragma unroll
                    for (int s2 = 0; s2 < 4; s2++) {
                        int j = (s2 << 6) + lane;
                        if (j > i && j < n && ((keepm >> s2) & 1u)) {
                            float xx1 = fmaxf(bix, bx[s2].x), yy1 = fmaxf(biy, bx[s2].y);
                            float xx2 = fminf(biz, bx[s2].z), yy2 = fminf(biw, bx[s2].w);
                            float inter = fmaxf(xx2 - xx1, 0.f) * fmaxf(yy2 - yy1, 0.f);
                            float uni = ai + area[s2] - inter;
                            if (inter / fmaxf(uni, 1e-9f) > NMS_THR_F) keepm &= ~(1u << s2);
                        }
                    }
                }
            }
        }
        #pragma unroll
        for (int s = 0; s < 4; s++) {
            int j = (s << 6) + lane;
            if (j < n) keepf[mylist[j]] = (keepm >> s) & 1u;
        }
    }
    __syncthreads();

    // ---- pick phase: wave 0 only ----
    if (wave == 0) {
        // probe refined_mask layout: int32 words are strictly 0/1; packed bool bytes are not
        unsigned any = 0;
        for (int i = lane; i < 4096; i += 64) if (refined_raw[i] > 1u) any = 1;
        unsigned mode = (__ballot(any != 0) != 0ULL) ? 1u : 0u;
        if (lane == 0) smode = mode;

        int base = 0;                                  // first-100 kept, in sorted order
        for (int c = 0; c < CAND; c += 64) {
            int i = c + lane;
            bool k = (i < CAND) && (keepf[i] != 0);
            unsigned long long bal = __ballot(k);
            int rank = __popcll(bal & ((1ULL << lane) - 1ULL));
            int pos = base + rank;
            if (k && pos < KSEL) { ss[pos] = cscore[i]; sf[pos] = cfeat[i]; }
            base += __popcll(bal);
        }
        if (lane == 0) sbase = base;
    }
    __syncthreads();

    if (tid == 0) {
        int nsel = min(sbase, KSEL), nslots = 0;
        for (int s = 0; s < KSEL; s++) {
            if (s < nsel) {
                int f = sf[s];
                int sl = q2s[f];
                if (sl < 0) { sl = nslots++; q2s[f] = sl; }
                sel_slot[s] = sl; sel_score[s] = ss[s];
            } else {
                sel_slot[s] = -1; sel_score[s] = 0.f;  // -inf pads -> exact 0 rows
            }
        }
        *mode_flag = smode;
    }
    __syncthreads();
    for (int q = tid; q < NQ; q += 1024) qry2slot[q] = q2s[q];
}

// ---------------- K3: 4M-pair scatter-max, 8 pairs/thread ----------------
// All input streams issued up-front (single memory epoch, no dependent
// conditional loads); qry->slot table staged in LDS; early-out kept only
// for the atomic phase.
__global__ __launch_bounds__(256) void k_scatter(
    const float4* __restrict__ seg4, const float4* __restrict__ xy4,
    const int4* __restrict__ qry4, const unsigned* __restrict__ refined_raw,
    const int* __restrict__ qry2slot, const unsigned* __restrict__ mode_flag,
    unsigned* __restrict__ maps)
{
    __shared__ int q2s[NQ];
    int tid = threadIdx.x;
    int t = blockIdx.x * 256 + tid;                    // 8-pair group index
    bool act = (t < (NPAIRS / 8));                     // 500,000 groups

    int4 qa = {0,0,0,0}, qb = {0,0,0,0};
    float4 sa = {0,0,0,0}, sb = {0,0,0,0};
    float4 x0 = {0,0,0,0}, x1 = {0,0,0,0}, x2 = {0,0,0,0}, x3 = {0,0,0,0};
    unsigned r0=0,r1=0,r2=0,r3=0,r4=0,r5=0,r6=0,r7=0;

    if (act) {
        qa = qry4[2*t];     qb = qry4[2*t+1];
        sa = seg4[2*t];     sb = seg4[2*t+1];
        x0 = xy4[4*t];      x1 = xy4[4*t+1];
        x2 = xy4[4*t+2];    x3 = xy4[4*t+3];
        unsigned mode = *mode_flag;                    // uniform scalar load
        if (mode) {                                    // packed bool bytes
            unsigned rw0 = refined_raw[2*t], rw1 = refined_raw[2*t+1];
            r0 = rw0 & 255u; r1 = (rw0 >> 8) & 255u; r2 = (rw0 >> 16) & 255u; r3 = rw0 >> 24;
            r4 = rw1 & 255u; r5 = (rw1 >> 8) & 255u; r6 = (rw1 >> 16) & 255u; r7 = rw1 >> 24;
        } else {                                       // int32 words
            uint4 rr0 = ((const uint4*)refined_raw)[2*t];
            uint4 rr1 = ((const uint4*)refined_raw)[2*t+1];
            r0 = rr0.x; r1 = rr0.y; r2 = rr0.z; r3 = rr0.w;
            r4 = rr1.x; r5 = rr1.y; r6 = rr1.z; r7 = rr1.w;
        }
    }

    for (int q = tid; q < NQ; q += 256) q2s[q] = qry2slot[q];
    __syncthreads();                                   // also drains the streamed loads
    if (!act) return;

    int s0 = q2s[qa.x], s1 = q2s[qa.y], s2 = q2s[qa.z], s3 = q2s[qa.w];
    int s4 = q2s[qb.x], s5 = q2s[qb.y], s6 = q2s[qb.z], s7 = q2s[qb.w];
    if ((s0 & s1 & s2 & s3 & s4 & s5 & s6 & s7) < 0) return;   // all 8 unselected

    #define DO_PAIR(S, PX, PY, W, R)                                              \
        if (S >= 0) {                                                             \
            int px = min(max((int)((PX) * 256.f), 0), 255);                       \
            int py = min(max((int)((PY) * 256.f), 0), 255);                       \
            float w = (R) ? 2.f * (W) : (W);                                      \
            atomicMax(&maps[S * FHW + py * 256 + px], enc_f32(w));                \
        }
    DO_PAIR(s0, x0.x, x0.y, sa.x, r0)
    DO_PAIR(s1, x0.z, x0.w, sa.y, r1)
    DO_PAIR(s2, x1.x, x1.y, sa.z, r2)
    DO_PAIR(s3, x1.z, x1.w, sa.w, r3)
    DO_PAIR(s4, x2.x, x2.y, sb.x, r4)
    DO_PAIR(s5, x2.z, x2.w, sb.y, r5)
    DO_PAIR(s6, x3.x, x3.y, sb.z, r6)
    DO_PAIR(s7, x3.z, x3.w, sb.w, r7)
    #undef DO_PAIR
}

// ---------------- K4: epilogue  out = score * sigmoid(map), 4 cells/thread --------
__global__ __launch_bounds__(256) void k_output(
    const uint4* __restrict__ maps4,
    const float* __restrict__ sel_score, const int* __restrict__ sel_slot,
    float4* __restrict__ out4)
{
    int i = blockIdx.x * 256 + threadIdx.x;            // 6400*256 == 1,638,400 exact
    int s = i >> 14;                                   // 16384 uint4 per segment
    float sc = sel_score[s];
    int slot = sel_slot[s];
    float4 v = {0.f, 0.f, 0.f, 0.f};
    if (slot >= 0) {
        uint4 m = maps4[slot * (FHW / 4) + (i & 16383)];
        v.x = sc / (1.f + expf(-dec_f32(m.x)));        // m=-1e4 -> exp=inf -> exactly 0
        v.y = sc / (1.f + expf(-dec_f32(m.y)));
        v.z = sc / (1.f + expf(-dec_f32(m.z)));
        v.w = sc / (1.f + expf(-dec_f32(m.w)));
    }
    out4[i] = v;
}

// ---------------- launch ----------------
extern "C" void kernel_launch(void* const* d_in, const int* in_sizes, int n_in,
                              void* d_out, int out_size, void* d_ws, size_t ws_size,
                              hipStream_t stream) {
    const float*    cls     = (const float*)d_in[0];
    const float*    pboxes  = (const float*)d_in[1];
    const float4*   seg4    = (const float4*)d_in[2];
    const float4*   xy4     = (const float4*)d_in[3];
    const int4*     qry4    = (const int4*)d_in[4];
    const unsigned* refined = (const unsigned*)d_in[5];
    // d_in[6] map_ids: unused by the reference
    float* out = (float*)d_out;

    char* ws = (char*)d_ws;
    unsigned*  maps      = (unsigned*)ws;                       // 100*65536*4 = 26,214,400 B
    float4*    cboxes    = (float4*)(ws + 26214400);            // 16,000 B (16-aligned)
    float*     cscore    = (float*) (ws + 26230400);            // 4,000 B
    int*       cfeat     = (int*)   (ws + 26234400);            // 4,000 B
    int*       clabel    = (int*)   (ws + 26238400);            // 4,000 B
    // 26242400..26246400 free (keepflag now lives in LDS)
    float*     sel_score = (float*) (ws + 26246400);            // 400 B
    int*       sel_slot  = (int*)   (ws + 26246800);            // 400 B
    int*       qry2slot  = (int*)   (ws + 26247200);            // 1,200 B
    unsigned*  mode_flag = (unsigned*)(ws + 26248400);          // 4 B

    k_init_select<<<1601, 1024, 0, stream>>>(cls, pboxes, cboxes, cscore, cfeat, clabel,
                                             (uint4*)maps);
    k_nms_pick   <<<1, 1024, 0, stream>>>(cboxes, clabel, cscore, cfeat,
                                          sel_score, sel_slot, qry2slot, refined, mode_flag);
    k_scatter    <<<1954, 256, 0, stream>>>(seg4, xy4, qry4, refined, qry2slot, mode_flag,
                                            (unsigned*)maps);
    k_output     <<<6400, 256, 0, stream>>>((const uint4*)maps, sel_score, sel_slot,
                                            (float4*)out);
}

// Round 2
// 257.834 us; speedup vs baseline: 1.0110x; 1.0110x over previous
//
#include <hip/hip_runtime.h>

// ---------------- problem constants ----------------
#define NQ        300
#define NC        80
#define NE        24000      // NQ*NC
#define CAND      1000
#define KSEL      100
#define NPAIRS    4000000
#define HB        4096       // score histogram buckets (float bits >> 18)
#define FHW       65536      // 256*256
#define NMS_THR_F 0.65f
#define MAPS_INIT 0x39E3BFFFu   // order-preserving encode of -1e4f

#define NBLK_A    977        // stage/bin blocks: 977*1024*4 pairs >= 4M
#define REC_CAP   2097152    // record capacity (expected ~1.3M; >500 sigma headroom)

// order-preserving float->u32 encode (monotone: larger float => larger uint)
__device__ __forceinline__ unsigned enc_f32(float f) {
    unsigned u = __float_as_uint(f);
    return (u & 0x80000000u) ? ~u : (u | 0x80000000u);
}
__device__ __forceinline__ float dec_f32(unsigned k) {
    unsigned u = (k & 0x80000000u) ? (k ^ 0x80000000u) : ~k;
    return __uint_as_float(u);
}

// ---------------- K1: sigmoid scores -> top-1000 sorted candidates ----------------
__global__ __launch_bounds__(1024) void k_select(
    const float* __restrict__ cls,        // [300,81]
    const float* __restrict__ pboxes,     // [300,4]
    float4* __restrict__ cboxes, float* __restrict__ cscore,
    int* __restrict__ cfeat, int* __restrict__ clabel,
    unsigned* __restrict__ gtail)
{
    __shared__ unsigned long long sbuf[4096];          // 32 KB, aliases hist
    unsigned* hist = (unsigned*)sbuf;                  // first 16 KB
    __shared__ unsigned subhist[64];
    __shared__ int sB, sT, sAbove, sCount, sN;
    int tid = threadIdx.x;

    if (tid == 0) *gtail = 0u;                         // reset record tail for k_stage

    for (int b = tid; b < HB; b += 1024) hist[b] = 0u;
    if (tid < 64) subhist[tid] = 0u;
    __syncthreads();

    unsigned long long lk[24];
    #pragma unroll
    for (int k = 0; k < 24; k++) {
        int e = tid + (k << 10);
        if (e < NE) {
            int q = e / NC, c = e - q * NC;
            float x = cls[q * (NC + 1) + c];
            float s = 1.f / (1.f + expf(-x));          // scores in (0,1) -> bits monotone
            unsigned bits = __float_as_uint(s);
            lk[k] = ((unsigned long long)bits << 32) | (unsigned)(0xFFFFFFFFu - (unsigned)e);
            atomicAdd(&hist[bits >> 18], 1u);
        }
    }
    __syncthreads();

    if (tid == 0) {
        int acc = 0, B = 0;
        for (int b = HB - 1; b >= 0; b--) {            // top buckets ~empty; ~50 iters
            acc += (int)hist[b];
            if (acc >= CAND) { B = b; break; }
        }
        sB = B; sAbove = acc - (int)hist[B]; sCount = 0;
    }
    __syncthreads();
    unsigned B = (unsigned)sB;

    #pragma unroll
    for (int k = 0; k < 24; k++) {                     // sub-histogram of bucket B
        int e = tid + (k << 10);
        if (e < NE && (unsigned)(lk[k] >> 50) == B)
            atomicAdd(&subhist[(unsigned)(lk[k] >> 44) & 63u], 1u);
    }
    __syncthreads();
    if (tid == 0) {
        int acc2 = sAbove, T = 0;
        for (int t = 63; t >= 0; t--) {
            acc2 += (int)subhist[t];
            if (acc2 >= CAND) { T = t; break; }
        }
        sT = T; sN = acc2;                             // n in [1000, 1000+subbucket]
    }
    __syncthreads();
    unsigned T = (unsigned)sT;

    #pragma unroll
    for (int k = 0; k < 24; k++) {                     // compact qualifying keys
        int e = tid + (k << 10);
        if (e < NE) {
            unsigned long long key = lk[k];
            unsigned bkt = (unsigned)(key >> 50);
            unsigned sub = (unsigned)(key >> 44) & 63u;
            if (bkt > B || (bkt == B && sub >= T)) {
                int pos = atomicAdd(&sCount, 1);
                if (pos < 4096) sbuf[pos] = key;
            }
        }
    }
    __syncthreads();
    int n = min(sN, 4096);

    if (n <= 1024) {
        // fast path: one key per thread, descending bitonic, shfl for j<64
        unsigned long long r = (tid < n) ? sbuf[tid] : 0ULL;
        for (int k = 2; k <= 1024; k <<= 1) {
            for (int j = k >> 1; j > 0; j >>= 1) {
                unsigned long long p;
                if (j >= 64) {
                    sbuf[tid] = r; __syncthreads();
                    p = sbuf[tid ^ j]; __syncthreads();
                } else {
                    p = __shfl_xor(r, j, 64);
                }
                bool d = (tid & k) != 0, lower = (tid & j) == 0;
                r = (d != lower) ? (r > p ? r : p) : (r < p ? r : p);
            }
        }
        sbuf[tid] = r;
        __syncthreads();
    } else {
        // fallback: generic LDS bitonic over next pow2
        int nsort = 2048; while (nsort < n) nsort <<= 1;
        for (int i = n + tid; i < nsort; i += 1024) sbuf[i] = 0ULL;
        __syncthreads();
        for (int k = 2; k <= nsort; k <<= 1) {
            for (int j = k >> 1; j > 0; j >>= 1) {
                for (int i = tid; i < nsort; i += 1024) {
                    int ixj = i ^ j;
                    if (ixj > i) {
                        unsigned long long a = sbuf[i], b = sbuf[ixj];
                        bool up = ((i & k) == 0);
                        if (up ? (a < b) : (a > b)) { sbuf[i] = b; sbuf[ixj] = a; }
                    }
                }
                __syncthreads();
            }
        }
    }

    if (tid < CAND) {
        unsigned long long key = sbuf[tid];
        unsigned bits = (unsigned)(key >> 32);
        unsigned e = 0xFFFFFFFFu - (unsigned)(key & 0xFFFFFFFFu);
        int feat = (int)e / NC, lab = (int)e - feat * NC;
        cscore[tid] = __uint_as_float(bits);
        cfeat[tid]  = feat;
        clabel[tid] = lab;
        float off = 4.f * (float)lab;                  // class-aware box offset
        float4 b;
        b.x = pboxes[feat * 4 + 0] + off; b.y = pboxes[feat * 4 + 1] + off;
        b.z = pboxes[feat * 4 + 2] + off; b.w = pboxes[feat * 4 + 3] + off;
        cboxes[tid] = b;
    }
}

// ---------------- K2: fused {per-label NMS + first-100 pick} ----------------
// one block, 1024 threads = 16 waves. Wave w handles labels w, w+16, ... (5 each).
__global__ __launch_bounds__(1024) void k_nms_pick(
    const float4* __restrict__ cboxes, const int* __restrict__ clabel,
    const float* __restrict__ cscore, const int* __restrict__ cfeat,
    float* __restrict__ sel_score, int* __restrict__ sel_slot,
    int* __restrict__ qry2slot,
    const unsigned* __restrict__ refined_raw, unsigned* __restrict__ mode_flag)
{
    __shared__ int list[16][256];                      // per-wave label member list
    __shared__ int keepf[CAND];
    __shared__ float ss[KSEL];
    __shared__ int   sf[KSEL];
    __shared__ int   q2s[NQ];
    __shared__ unsigned smode;
    __shared__ int sbase;

    int tid  = threadIdx.x;
    int wave = tid >> 6, lane = tid & 63;
    int* mylist = list[wave];

    for (int i = tid; i < CAND; i += 1024) keepf[i] = 0;   // labels with >256 members: tail dropped
    for (int q = tid; q < NQ; q += 1024) q2s[q] = -1;
    __syncthreads();

    for (int lab = wave; lab < NC; lab += 16) {
        int base = 0;
        for (int c = 0; c < CAND; c += 64) {           // ordered compaction of this label
            int i = c + lane;
            bool m = (i < CAND) && (clabel[i] == lab);
            unsigned long long bal = __ballot(m);
            int rank = __popcll(bal & ((1ULL << lane) - 1ULL));
            if (m && base + rank < 256) mylist[base + rank] = i;
            base += __popcll(bal);
        }
        int n = min(base, 256);

        float4 bx[4]; float area[4];
        unsigned keepm = 0;
        #pragma unroll
        for (int s = 0; s < 4; s++) {
            int j = (s << 6) + lane;
            if (j < n) {
                bx[s] = cboxes[mylist[j]];
                area[s] = (bx[s].z - bx[s].x) * (bx[s].w - bx[s].y);
                keepm |= (1u << s);
            }
        }
        #pragma unroll
        for (int slot = 0; slot < 4; slot++) {         // sequential greedy over this label
            int i0 = slot << 6;
            if (i0 >= n) break;
            int iend = min(64, n - i0);
            for (int l = 0; l < iend; l++) {
                int i = i0 + l;
                unsigned km = __shfl(keepm, l);
                bool keep_i = (km >> slot) & 1u;       // uniform
                float bix = __shfl(bx[slot].x, l), biy = __shfl(bx[slot].y, l);
                float biz = __shfl(bx[slot].z, l), biw = __shfl(bx[slot].w, l);
                float ai  = __shfl(area[slot], l);
                if (keep_i) {
                    #pragma unroll
                    for (int s2 = 0; s2 < 4; s2++) {
                        int j = (s2 << 6) + lane;
                        if (j > i && j < n && ((keepm >> s2) & 1u)) {
                            float xx1 = fmaxf(bix, bx[s2].x), yy1 = fmaxf(biy, bx[s2].y);
                            float xx2 = fminf(biz, bx[s2].z), yy2 = fminf(biw, bx[s2].w);
                            float inter = fmaxf(xx2 - xx1, 0.f) * fmaxf(yy2 - yy1, 0.f);
                            float uni = ai + area[s2] - inter;
                            if (inter / fmaxf(uni, 1e-9f) > NMS_THR_F) keepm &= ~(1u << s2);
                        }
                    }
                }
            }
        }
        #pragma unroll
        for (int s = 0; s < 4; s++) {
            int j = (s << 6) + lane;
            if (j < n) keepf[mylist[j]] = (keepm >> s) & 1u;
        }
    }
    __syncthreads();

    // ---- pick phase: wave 0 only ----
    if (wave == 0) {
        // probe refined_mask layout: int32 words are strictly 0/1; packed bool bytes are not
        unsigned any = 0;
        for (int i = lane; i < 4096; i += 64) if (refined_raw[i] > 1u) any = 1;
        unsigned mode = (__ballot(any != 0) != 0ULL) ? 1u : 0u;
        if (lane == 0) smode = mode;

        int base = 0;                                  // first-100 kept, in sorted order
        for (int c = 0; c < CAND; c += 64) {
            int i = c + lane;
            bool k = (i < CAND) && (keepf[i] != 0);
            unsigned long long bal = __ballot(k);
            int rank = __popcll(bal & ((1ULL << lane) - 1ULL));
            int pos = base + rank;
            if (k && pos < KSEL) { ss[pos] = cscore[i]; sf[pos] = cfeat[i]; }
            base += __popcll(bal);
        }
        if (lane == 0) sbase = base;
    }
    __syncthreads();

    if (tid == 0) {
        int nsel = min(sbase, KSEL), nslots = 0;
        for (int s = 0; s < KSEL; s++) {
            if (s < nsel) {
                int f = sf[s];
                int sl = q2s[f];
                if (sl < 0) { sl = nslots++; q2s[f] = sl; }
                sel_slot[s] = sl; sel_score[s] = ss[s];
            } else {
                sel_slot[s] = -1; sel_score[s] = 0.f;  // -inf pads -> exact 0 rows
            }
        }
        *mode_flag = smode;
    }
    __syncthreads();
    for (int q = tid; q < NQ; q += 1024) qry2slot[q] = q2s[q];
}

// ---------------- K3a: stage active pairs as 8B records + per-block slot hist ----
// record = (encw << 32) | (slot<<16 | py<<8 | px). One global atomicAdd per block.
__global__ __launch_bounds__(1024) void k_stage(
    const float4* __restrict__ seg4, const float4* __restrict__ xy4,
    const int4* __restrict__ qry4, const unsigned* __restrict__ refined_raw,
    const int* __restrict__ qry2slot, const unsigned* __restrict__ mode_flag,
    unsigned long long* __restrict__ rec0,
    unsigned* __restrict__ H, int* __restrict__ basev, int* __restrict__ cntv,
    unsigned* __restrict__ gtail)
{
    __shared__ unsigned hist[KSEL];
    __shared__ int scnt, sgbase;
    int tid = threadIdx.x, b = blockIdx.x;
    if (tid < KSEL) hist[tid] = 0u;
    if (tid == 0) scnt = 0;
    __syncthreads();

    int t = b * 1024 + tid;                            // 4-pair group index
    unsigned addr[4]; unsigned encw[4]; int nloc = 0;
    if (t < (NPAIRS / 4)) {
        int4 q = qry4[t];
        int s0 = qry2slot[q.x], s1 = qry2slot[q.y];
        int s2 = qry2slot[q.z], s3 = qry2slot[q.w];
        if ((s0 & s1 & s2 & s3) < 0 ? (s0 >= 0 || s1 >= 0 || s2 >= 0 || s3 >= 0) : true) {
            float4 sg   = seg4[t];
            float4 xy01 = xy4[2 * t], xy23 = xy4[2 * t + 1];
            unsigned r0, r1, r2, r3;
            if (*mode_flag) {                          // packed bool bytes
                unsigned rb = refined_raw[t];
                r0 = rb & 255u; r1 = (rb >> 8) & 255u; r2 = (rb >> 16) & 255u; r3 = rb >> 24;
            } else {                                   // int32 words
                uint4 rr = ((const uint4*)refined_raw)[t];
                r0 = rr.x; r1 = rr.y; r2 = rr.z; r3 = rr.w;
            }
            #define MK_REC(S, PX, PY, W, R)                                       \
                if (S >= 0) {                                                     \
                    int px = min(max((int)((PX) * 256.f), 0), 255);               \
                    int py = min(max((int)((PY) * 256.f), 0), 255);               \
                    float w = (R) ? 2.f * (W) : (W);                              \
                    addr[nloc] = ((unsigned)S << 16) | ((unsigned)py << 8) | (unsigned)px; \
                    encw[nloc] = enc_f32(w);                                      \
                    nloc++;                                                       \
                }
            MK_REC(s0, xy01.x, xy01.y, sg.x, r0)
            MK_REC(s1, xy01.z, xy01.w, sg.y, r1)
            MK_REC(s2, xy23.x, xy23.y, sg.z, r2)
            MK_REC(s3, xy23.z, xy23.w, sg.w, r3)
            #undef MK_REC
        }
    }
    int myofs = (nloc > 0) ? atomicAdd(&scnt, nloc) : 0;
    __syncthreads();
    if (tid == 0) sgbase = (int)atomicAdd(gtail, (unsigned)scnt);
    __syncthreads();
    int gb = sgbase;

    for (int k = 0; k < nloc; k++) {
        int pos = gb + myofs + k;
        if (pos < REC_CAP) {
            rec0[pos] = ((unsigned long long)encw[k] << 32) | addr[k];
            atomicAdd(&hist[addr[k] >> 16], 1u);       // hist counts only written records
        }
    }
    __syncthreads();
    if (tid < KSEL) H[tid * NBLK_A + b] = hist[tid];   // [slot][block] layout
    if (tid == 0) {
        basev[b] = gb;
        int wr = REC_CAP - gb; if (wr < 0) wr = 0; if (wr > scnt) wr = scnt;
        cntv[b] = wr;
    }
}

// ---------------- K3b: per-slot exclusive scan of H across blocks ----------------
__global__ __launch_bounds__(1024) void k_scanH(
    const unsigned* __restrict__ H, unsigned* __restrict__ OFF,
    unsigned* __restrict__ total)
{
    __shared__ unsigned arr[1024];
    int s = blockIdx.x, tid = threadIdx.x;
    unsigned v = (tid < NBLK_A) ? H[s * NBLK_A + tid] : 0u;
    arr[tid] = v;
    __syncthreads();
    for (int d = 1; d < 1024; d <<= 1) {
        unsigned t = (tid >= d) ? arr[tid - d] : 0u;
        __syncthreads();
        arr[tid] += t;
        __syncthreads();
    }
    if (tid < NBLK_A) OFF[s * NBLK_A + tid] = arr[tid] - v;   // exclusive
    if (tid == 1023) total[s] = arr[1023];
}

// ---------------- K3c: permute records into slot-contiguous bins ----------------
__global__ __launch_bounds__(1024) void k_bin(
    const unsigned long long* __restrict__ rec0,
    const unsigned* __restrict__ OFF, const unsigned* __restrict__ total,
    const int* __restrict__ basev, const int* __restrict__ cntv,
    unsigned long long* __restrict__ rec1)
{
    __shared__ unsigned c2[KSEL], offs[KSEL], sstart[KSEL];
    int tid = threadIdx.x, b = blockIdx.x;
    if (tid < KSEL) { c2[tid] = 0u; offs[tid] = OFF[tid * NBLK_A + b]; }
    __syncthreads();
    if (tid == 0) {
        unsigned a = 0;
        for (int s = 0; s < KSEL; s++) { sstart[s] = a; a += total[s]; }
    }
    __syncthreads();

    int cb = cntv[b], bs = basev[b];
    for (int j = tid; j < cb; j += 1024) {
        unsigned long long r = rec0[bs + j];
        unsigned s = ((unsigned)r) >> 16;
        unsigned rank = atomicAdd(&c2[s], 1u);
        rec1[sstart[s] + offs[s] + rank] = r;
    }
}

// ---------------- K3d: per (selection, 1/8 tile): LDS max + fused sigmoid out ----
// 800 blocks: i = blk>>3 (selection), h = blk&7 (32-row band). 32KB LDS tile.
__global__ __launch_bounds__(1024) void k_tile_out(
    const unsigned long long* __restrict__ rec1,
    const unsigned* __restrict__ total,
    const float* __restrict__ sel_score, const int* __restrict__ sel_slot,
    float4* __restrict__ out4)
{
    __shared__ unsigned tile[8192];                    // 32 rows x 256 cols
    __shared__ unsigned sstart[KSEL];
    int tid = threadIdx.x;
    int i = blockIdx.x >> 3, h = blockIdx.x & 7;
    int slot = sel_slot[i];
    float sc = sel_score[i];
    long obase = (long)i * (FHW / 4) + h * 2048;       // float4 index

    if (slot < 0) {                                    // pad selection -> exact zero rows
        float4 z = {0.f, 0.f, 0.f, 0.f};
        out4[obase + tid] = z;
        out4[obase + 1024 + tid] = z;
        return;
    }

    #pragma unroll
    for (int k = 0; k < 8; k++) tile[tid + (k << 10)] = MAPS_INIT;
    if (tid == 0) {
        unsigned a = 0;
        for (int s = 0; s < KSEL; s++) { sstart[s] = a; a += total[s]; }
    }
    __syncthreads();

    unsigned ss = sstart[slot], tot = total[slot];
    for (unsigned j = tid; j < tot; j += 1024) {
        unsigned long long r = rec1[ss + j];
        unsigned addr = (unsigned)r;
        if (((addr >> 13) & 7u) == (unsigned)h)        // py>>5 == h
            atomicMax(&tile[addr & 8191u], (unsigned)(r >> 32));
    }
    __syncthreads();

    #pragma unroll
    for (int k = 0; k < 2; k++) {
        int j = tid + (k << 10);                       // float4 index within band
        unsigned m0 = tile[4 * j + 0], m1 = tile[4 * j + 1];
        unsigned m2 = tile[4 * j + 2], m3 = tile[4 * j + 3];
        float4 v;
        v.x = sc / (1.f + expf(-dec_f32(m0)));         // m=-1e4 -> exp=inf -> exactly 0
        v.y = sc / (1.f + expf(-dec_f32(m1)));
        v.z = sc / (1.f + expf(-dec_f32(m2)));
        v.w = sc / (1.f + expf(-dec_f32(m3)));
        out4[obase + j] = v;
    }
}

// ---------------- launch ----------------
extern "C" void kernel_launch(void* const* d_in, const int* in_sizes, int n_in,
                              void* d_out, int out_size, void* d_ws, size_t ws_size,
                              hipStream_t stream) {
    const float*    cls     = (const float*)d_in[0];
    const float*    pboxes  = (const float*)d_in[1];
    const float4*   seg4    = (const float4*)d_in[2];
    const float4*   xy4     = (const float4*)d_in[3];
    const int4*     qry4    = (const int4*)d_in[4];
    const unsigned* refined = (const unsigned*)d_in[5];
    // d_in[6] map_ids: unused by the reference
    float* out = (float*)d_out;

    char* ws = (char*)d_ws;
    unsigned long long* rec0 = (unsigned long long*)ws;         // 16,777,216 B
    unsigned long long* rec1 = (unsigned long long*)(ws + 16777216);  // 16,777,216 B
    unsigned*  H         = (unsigned*)(ws + 33554432);          // 100*977*4 = 390,800 B
    unsigned*  OFF       = (unsigned*)(ws + 33945232);          // 390,800 B
    unsigned*  total     = (unsigned*)(ws + 34336032);          // 400 B
    int*       basev     = (int*)     (ws + 34336432);          // 3,908 B
    int*       cntv      = (int*)     (ws + 34340340);          // 3,908 B
    unsigned*  gtail     = (unsigned*)(ws + 34344248);          // 4 B
    float4*    cboxes    = (float4*)  (ws + 34344256);          // 16,000 B (16-aligned)
    float*     cscore    = (float*)   (ws + 34360256);          // 4,000 B
    int*       cfeat     = (int*)     (ws + 34364256);          // 4,000 B
    int*       clabel    = (int*)     (ws + 34368256);          // 4,000 B
    float*     sel_score = (float*)   (ws + 34372256);          // 400 B
    int*       sel_slot  = (int*)     (ws + 34372656);          // 400 B
    int*       qry2slot  = (int*)     (ws + 34373056);          // 1,200 B
    unsigned*  mode_flag = (unsigned*)(ws + 34374256);          // 4 B

    k_select  <<<1, 1024, 0, stream>>>(cls, pboxes, cboxes, cscore, cfeat, clabel, gtail);
    k_nms_pick<<<1, 1024, 0, stream>>>(cboxes, clabel, cscore, cfeat,
                                       sel_score, sel_slot, qry2slot, refined, mode_flag);
    k_stage   <<<NBLK_A, 1024, 0, stream>>>(seg4, xy4, qry4, refined, qry2slot, mode_flag,
                                            rec0, H, basev, cntv, gtail);
    k_scanH   <<<KSEL, 1024, 0, stream>>>(H, OFF, total);
    k_bin     <<<NBLK_A, 1024, 0, stream>>>(rec0, OFF, total, basev, cntv, rec1);
    k_tile_out<<<KSEL * 8, 1024, 0, stream>>>(rec1, total, sel_score, sel_slot,
                                              (float4*)out);
}

// Round 3
// 242.491 us; speedup vs baseline: 1.0750x; 1.0633x over previous
//
#include <hip/hip_runtime.h>

// ---------------- problem constants ----------------
#define NQ        300
#define NC        80
#define NE        24000      // NQ*NC
#define CAND      1000
#define KSEL      100
#define NPAIRS    4000000
#define HB        4096       // score histogram buckets (float bits >> 18)
#define FHW       65536      // 256*256
#define NMS_THR_F 0.65f
#define MAPS_INIT 0x39E3BFFFu   // order-preserving encode of -1e4f

#define NBLK_A    977        // stage blocks: 977*1024*4 pairs >= 4M
#define SLOT_CAP  32768      // per-slot record capacity (expected ~13.4K; huge headroom)

// order-preserving float->u32 encode (monotone: larger float => larger uint)
__device__ __forceinline__ unsigned enc_f32(float f) {
    unsigned u = __float_as_uint(f);
    return (u & 0x80000000u) ? ~u : (u | 0x80000000u);
}
__device__ __forceinline__ float dec_f32(unsigned k) {
    unsigned u = (k & 0x80000000u) ? (k ^ 0x80000000u) : ~k;
    return __uint_as_float(u);
}

// ---------------- K1: sigmoid scores -> top-1000 sorted candidates ----------------
__global__ __launch_bounds__(1024) void k_select(
    const float* __restrict__ cls,        // [300,81]
    const float* __restrict__ pboxes,     // [300,4]
    float4* __restrict__ cboxes, float* __restrict__ cscore,
    int* __restrict__ cfeat, int* __restrict__ clabel,
    unsigned* __restrict__ slot_tail)
{
    __shared__ unsigned long long sbuf[4096];          // 32 KB, aliases hist
    unsigned* hist = (unsigned*)sbuf;                  // first 16 KB
    __shared__ unsigned subhist[64];
    __shared__ int sB, sT, sAbove, sCount, sN;
    int tid = threadIdx.x;

    if (tid < KSEL) slot_tail[tid] = 0u;               // reset per-slot bin tails

    for (int b = tid; b < HB; b += 1024) hist[b] = 0u;
    if (tid < 64) subhist[tid] = 0u;
    __syncthreads();

    unsigned long long lk[24];
    #pragma unroll
    for (int k = 0; k < 24; k++) {
        int e = tid + (k << 10);
        if (e < NE) {
            int q = e / NC, c = e - q * NC;
            float x = cls[q * (NC + 1) + c];
            float s = 1.f / (1.f + expf(-x));          // scores in (0,1) -> bits monotone
            unsigned bits = __float_as_uint(s);
            lk[k] = ((unsigned long long)bits << 32) | (unsigned)(0xFFFFFFFFu - (unsigned)e);
            atomicAdd(&hist[bits >> 18], 1u);
        }
    }
    __syncthreads();

    if (tid == 0) {
        int acc = 0, B = 0;
        for (int b = HB - 1; b >= 0; b--) {            // top buckets ~empty; ~50 iters
            acc += (int)hist[b];
            if (acc >= CAND) { B = b; break; }
        }
        sB = B; sAbove = acc - (int)hist[B]; sCount = 0;
    }
    __syncthreads();
    unsigned B = (unsigned)sB;

    #pragma unroll
    for (int k = 0; k < 24; k++) {                     // sub-histogram of bucket B
        int e = tid + (k << 10);
        if (e < NE && (unsigned)(lk[k] >> 50) == B)
            atomicAdd(&subhist[(unsigned)(lk[k] >> 44) & 63u], 1u);
    }
    __syncthreads();
    if (tid == 0) {
        int acc2 = sAbove, T = 0;
        for (int t = 63; t >= 0; t--) {
            acc2 += (int)subhist[t];
            if (acc2 >= CAND) { T = t; break; }
        }
        sT = T; sN = acc2;                             // n in [1000, 1000+subbucket]
    }
    __syncthreads();
    unsigned T = (unsigned)sT;

    #pragma unroll
    for (int k = 0; k < 24; k++) {                     // compact qualifying keys
        int e = tid + (k << 10);
        if (e < NE) {
            unsigned long long key = lk[k];
            unsigned bkt = (unsigned)(key >> 50);
            unsigned sub = (unsigned)(key >> 44) & 63u;
            if (bkt > B || (bkt == B && sub >= T)) {
                int pos = atomicAdd(&sCount, 1);
                if (pos < 4096) sbuf[pos] = key;
            }
        }
    }
    __syncthreads();
    int n = min(sN, 4096);

    if (n <= 1024) {
        // fast path: one key per thread, descending bitonic, shfl for j<64
        unsigned long long r = (tid < n) ? sbuf[tid] : 0ULL;
        for (int k = 2; k <= 1024; k <<= 1) {
            for (int j = k >> 1; j > 0; j >>= 1) {
                unsigned long long p;
                if (j >= 64) {
                    sbuf[tid] = r; __syncthreads();
                    p = sbuf[tid ^ j]; __syncthreads();
                } else {
                    p = __shfl_xor(r, j, 64);
                }
                bool d = (tid & k) != 0, lower = (tid & j) == 0;
                r = (d != lower) ? (r > p ? r : p) : (r < p ? r : p);
            }
        }
        sbuf[tid] = r;
        __syncthreads();
    } else {
        // fallback: generic LDS bitonic over next pow2
        int nsort = 2048; while (nsort < n) nsort <<= 1;
        for (int i = n + tid; i < nsort; i += 1024) sbuf[i] = 0ULL;
        __syncthreads();
        for (int k = 2; k <= nsort; k <<= 1) {
            for (int j = k >> 1; j > 0; j >>= 1) {
                for (int i = tid; i < nsort; i += 1024) {
                    int ixj = i ^ j;
                    if (ixj > i) {
                        unsigned long long a = sbuf[i], b = sbuf[ixj];
                        bool up = ((i & k) == 0);
                        if (up ? (a < b) : (a > b)) { sbuf[i] = b; sbuf[ixj] = a; }
                    }
                }
                __syncthreads();
            }
        }
    }

    if (tid < CAND) {
        unsigned long long key = sbuf[tid];
        unsigned bits = (unsigned)(key >> 32);
        unsigned e = 0xFFFFFFFFu - (unsigned)(key & 0xFFFFFFFFu);
        int feat = (int)e / NC, lab = (int)e - feat * NC;
        cscore[tid] = __uint_as_float(bits);
        cfeat[tid]  = feat;
        clabel[tid] = lab;
        float off = 4.f * (float)lab;                  // class-aware box offset
        float4 b;
        b.x = pboxes[feat * 4 + 0] + off; b.y = pboxes[feat * 4 + 1] + off;
        b.z = pboxes[feat * 4 + 2] + off; b.w = pboxes[feat * 4 + 3] + off;
        cboxes[tid] = b;
    }
}

// ---------------- K2: per-label greedy NMS, one wave per label (parallel) --------
__global__ __launch_bounds__(64) void k_nms(
    const float4* __restrict__ cboxes, const int* __restrict__ clabel,
    int* __restrict__ keepflag)
{
    int lab = blockIdx.x, lane = threadIdx.x;
    __shared__ int list[256];
    int base = 0;
    for (int c = 0; c < CAND; c += 64) {               // ordered compaction of this label
        int i = c + lane;
        bool m = (i < CAND) && (clabel[i] == lab);
        unsigned long long bal = __ballot(m);
        int rank = __popcll(bal & ((1ULL << lane) - 1ULL));
        if (m && base + rank < 256) list[base + rank] = i;
        base += __popcll(bal);
    }
    __syncthreads();
    int n = min(base, 256);

    float4 bx[4]; float area[4];
    unsigned keepm = 0;
    #pragma unroll
    for (int s = 0; s < 4; s++) {
        int j = (s << 6) + lane;
        if (j < n) {
            bx[s] = cboxes[list[j]];
            area[s] = (bx[s].z - bx[s].x) * (bx[s].w - bx[s].y);
            keepm |= (1u << s);
        }
    }
    #pragma unroll
    for (int slot = 0; slot < 4; slot++) {             // sequential greedy over this label
        int i0 = slot << 6;
        if (i0 >= n) break;
        int iend = min(64, n - i0);
        for (int l = 0; l < iend; l++) {
            int i = i0 + l;
            unsigned km = __shfl(keepm, l);
            bool keep_i = (km >> slot) & 1u;           // uniform
            float bix = __shfl(bx[slot].x, l), biy = __shfl(bx[slot].y, l);
            float biz = __shfl(bx[slot].z, l), biw = __shfl(bx[slot].w, l);
            float ai  = __shfl(area[slot], l);
            if (keep_i) {
                #pragma unroll
                for (int s2 = 0; s2 < 4; s2++) {
                    int j = (s2 << 6) + lane;
                    if (j > i && j < n && ((keepm >> s2) & 1u)) {
                        float xx1 = fmaxf(bix, bx[s2].x), yy1 = fmaxf(biy, bx[s2].y);
                        float xx2 = fminf(biz, bx[s2].z), yy2 = fminf(biw, bx[s2].w);
                        float inter = fmaxf(xx2 - xx1, 0.f) * fmaxf(yy2 - yy1, 0.f);
                        float uni = ai + area[s2] - inter;
                        if (inter / fmaxf(uni, 1e-9f) > NMS_THR_F) keepm &= ~(1u << s2);
                    }
                }
            }
        }
    }
    #pragma unroll
    for (int s = 0; s < 4; s++) {
        int j = (s << 6) + lane;
        if (j < n) keepflag[list[j]] = (keepm >> s) & 1u;
    }
}

// ---------------- K3: pick first-100 kept, build query->slot table, dtype probe ----
__global__ __launch_bounds__(64) void k_pick(
    const float* __restrict__ cscore, const int* __restrict__ cfeat,
    const int* __restrict__ keepflag,
    float* __restrict__ sel_score, int* __restrict__ sel_slot,
    int* __restrict__ qry2slot,
    const unsigned* __restrict__ refined_raw, unsigned* __restrict__ mode_flag)
{
    int lane = threadIdx.x;
    __shared__ float ss[KSEL];
    __shared__ int   sf[KSEL];
    __shared__ int   q2s[NQ];

    // probe refined_mask layout: int32 words are strictly 0/1; packed bool bytes are not
    unsigned any = 0;
    for (int i = lane; i < 4096; i += 64) if (refined_raw[i] > 1u) any = 1;
    unsigned mode = (__ballot(any != 0) != 0ULL) ? 1u : 0u;

    int base = 0;                                      // first-100 kept, in sorted order
    for (int c = 0; c < CAND; c += 64) {
        int i = c + lane;
        bool k = (i < CAND) && (keepflag[i] != 0);
        unsigned long long bal = __ballot(k);
        int rank = __popcll(bal & ((1ULL << lane) - 1ULL));
        int pos = base + rank;
        if (k && pos < KSEL) { ss[pos] = cscore[i]; sf[pos] = cfeat[i]; }
        base += __popcll(bal);
    }
    for (int q = lane; q < NQ; q += 64) q2s[q] = -1;
    __syncthreads();
    if (lane == 0) {
        int nsel = min(base, KSEL), nslots = 0;
        for (int s = 0; s < KSEL; s++) {
            if (s < nsel) {
                int f = sf[s];
                int sl = q2s[f];
                if (sl < 0) { sl = nslots++; q2s[f] = sl; }
                sel_slot[s] = sl; sel_score[s] = ss[s];
            } else {
                sel_slot[s] = -1; sel_score[s] = 0.f;  // -inf pads -> exact 0 rows
            }
        }
        *mode_flag = mode;
    }
    __syncthreads();
    for (int q = lane; q < NQ; q += 64) qry2slot[q] = q2s[q];
}

// ---------------- K4: stage active pairs directly into per-slot bins ----------
// record = (encw << 32) | (slot<<16 | py<<8 | px).
// per-block LDS hist -> one global atomicAdd per (block,slot) -> direct write.
// order within a slot is non-deterministic; harmless (max is commutative).
__global__ __launch_bounds__(1024) void k_stage(
    const float4* __restrict__ seg4, const float4* __restrict__ xy4,
    const int4* __restrict__ qry4, const unsigned* __restrict__ refined_raw,
    const int* __restrict__ qry2slot, const unsigned* __restrict__ mode_flag,
    unsigned long long* __restrict__ bins, unsigned* __restrict__ slot_tail)
{
    __shared__ unsigned hist[KSEL];
    __shared__ unsigned gbase[KSEL];
    int tid = threadIdx.x, b = blockIdx.x;
    if (tid < KSEL) hist[tid] = 0u;
    __syncthreads();

    int t = b * 1024 + tid;                            // 4-pair group index
    unsigned addr[4], encw[4], rnk[4]; int nloc = 0;
    if (t < (NPAIRS / 4)) {
        int4 q = qry4[t];
        int s0 = qry2slot[q.x], s1 = qry2slot[q.y];
        int s2 = qry2slot[q.z], s3 = qry2slot[q.w];
        if ((s0 & s1 & s2 & s3) >= 0 || s0 >= 0 || s1 >= 0 || s2 >= 0 || s3 >= 0) {
            float4 sg   = seg4[t];
            float4 xy01 = xy4[2 * t], xy23 = xy4[2 * t + 1];
            unsigned r0, r1, r2, r3;
            if (*mode_flag) {                          // packed bool bytes
                unsigned rb = refined_raw[t];
                r0 = rb & 255u; r1 = (rb >> 8) & 255u; r2 = (rb >> 16) & 255u; r3 = rb >> 24;
            } else {                                   // int32 words
                uint4 rr = ((const uint4*)refined_raw)[t];
                r0 = rr.x; r1 = rr.y; r2 = rr.z; r3 = rr.w;
            }
            #define MK_REC(S, PX, PY, W, R)                                       \
                if (S >= 0) {                                                     \
                    int px = min(max((int)((PX) * 256.f), 0), 255);               \
                    int py = min(max((int)((PY) * 256.f), 0), 255);               \
                    float w = (R) ? 2.f * (W) : (W);                              \
                    addr[nloc] = ((unsigned)S << 16) | ((unsigned)py << 8) | (unsigned)px; \
                    encw[nloc] = enc_f32(w);                                      \
                    rnk[nloc]  = atomicAdd(&hist[S], 1u);                         \
                    nloc++;                                                       \
                }
            MK_REC(s0, xy01.x, xy01.y, sg.x, r0)
            MK_REC(s1, xy01.z, xy01.w, sg.y, r1)
            MK_REC(s2, xy23.x, xy23.y, sg.z, r2)
            MK_REC(s3, xy23.z, xy23.w, sg.w, r3)
            #undef MK_REC
        }
    }
    __syncthreads();
    if (tid < KSEL && hist[tid] > 0u)
        gbase[tid] = atomicAdd(&slot_tail[tid], hist[tid]);
    __syncthreads();

    for (int k = 0; k < nloc; k++) {
        unsigned s = addr[k] >> 16;
        unsigned pos = gbase[s] + rnk[k];
        if (pos < SLOT_CAP)
            bins[(size_t)s * SLOT_CAP + pos] =
                ((unsigned long long)encw[k] << 32) | addr[k];
    }
}

// ---------------- K5: per (selection, 1/8 tile): LDS max + fused sigmoid out ----
// 800 blocks: i = blk>>3 (selection), h = blk&7 (32-row band). 32KB LDS tile.
__global__ __launch_bounds__(1024) void k_tile_out(
    const unsigned long long* __restrict__ bins,
    const unsigned* __restrict__ slot_tail,
    const float* __restrict__ sel_score, const int* __restrict__ sel_slot,
    float4* __restrict__ out4)
{
    __shared__ unsigned tile[8192];                    // 32 rows x 256 cols
    int tid = threadIdx.x;
    int i = blockIdx.x >> 3, h = blockIdx.x & 7;
    int slot = sel_slot[i];
    float sc = sel_score[i];
    long obase = (long)i * (FHW / 4) + h * 2048;       // float4 index

    if (slot < 0) {                                    // pad selection -> exact zero rows
        float4 z = {0.f, 0.f, 0.f, 0.f};
        out4[obase + tid] = z;
        out4[obase + 1024 + tid] = z;
        return;
    }

    #pragma unroll
    for (int k = 0; k < 8; k++) tile[tid + (k << 10)] = MAPS_INIT;
    __syncthreads();

    unsigned tot = min(slot_tail[slot], (unsigned)SLOT_CAP);
    const unsigned long long* seg = bins + (size_t)slot * SLOT_CAP;
    for (unsigned j = tid; j < tot; j += 1024) {
        unsigned long long r = seg[j];
        unsigned addr = (unsigned)r;
        if (((addr >> 13) & 7u) == (unsigned)h)        // py>>5 == h
            atomicMax(&tile[addr & 8191u], (unsigned)(r >> 32));
    }
    __syncthreads();

    #pragma unroll
    for (int k = 0; k < 2; k++) {
        int j = tid + (k << 10);                       // float4 index within band
        unsigned m0 = tile[4 * j + 0], m1 = tile[4 * j + 1];
        unsigned m2 = tile[4 * j + 2], m3 = tile[4 * j + 3];
        float4 v;
        v.x = sc / (1.f + expf(-dec_f32(m0)));         // m=-1e4 -> exp=inf -> exactly 0
        v.y = sc / (1.f + expf(-dec_f32(m1)));
        v.z = sc / (1.f + expf(-dec_f32(m2)));
        v.w = sc / (1.f + expf(-dec_f32(m3)));
        out4[obase + j] = v;
    }
}

// ---------------- launch ----------------
extern "C" void kernel_launch(void* const* d_in, const int* in_sizes, int n_in,
                              void* d_out, int out_size, void* d_ws, size_t ws_size,
                              hipStream_t stream) {
    const float*    cls     = (const float*)d_in[0];
    const float*    pboxes  = (const float*)d_in[1];
    const float4*   seg4    = (const float4*)d_in[2];
    const float4*   xy4     = (const float4*)d_in[3];
    const int4*     qry4    = (const int4*)d_in[4];
    const unsigned* refined = (const unsigned*)d_in[5];
    // d_in[6] map_ids: unused by the reference
    float* out = (float*)d_out;

    char* ws = (char*)d_ws;
    unsigned long long* bins = (unsigned long long*)ws;         // 100*32768*8 = 26,214,400 B
    unsigned*  slot_tail = (unsigned*)(ws + 26214400);          // 400 B
    float4*    cboxes    = (float4*)  (ws + 26214800);          // 16,000 B (16-aligned)
    float*     cscore    = (float*)   (ws + 26230800);          // 4,000 B
    int*       cfeat     = (int*)     (ws + 26234800);          // 4,000 B
    int*       clabel    = (int*)     (ws + 26238800);          // 4,000 B
    int*       keepflag  = (int*)     (ws + 26242800);          // 4,000 B
    float*     sel_score = (float*)   (ws + 26246800);          // 400 B
    int*       sel_slot  = (int*)     (ws + 26247200);          // 400 B
    int*       qry2slot  = (int*)     (ws + 26247600);          // 1,200 B
    unsigned*  mode_flag = (unsigned*)(ws + 26248800);          // 4 B

    k_select  <<<1, 1024, 0, stream>>>(cls, pboxes, cboxes, cscore, cfeat, clabel,
                                       slot_tail);
    k_nms     <<<NC, 64, 0, stream>>>(cboxes, clabel, keepflag);
    k_pick    <<<1, 64, 0, stream>>>(cscore, cfeat, keepflag, sel_score, sel_slot,
                                     qry2slot, refined, mode_flag);
    k_stage   <<<NBLK_A, 1024, 0, stream>>>(seg4, xy4, qry4, refined, qry2slot, mode_flag,
                                            bins, slot_tail);
    k_tile_out<<<KSEL * 8, 1024, 0, stream>>>(bins, slot_tail, sel_score, sel_slot,
                                              (float4*)out);
}